// Round 1
// baseline (177.114 us; speedup 1.0000x reference)
//
#include <hip/hip_runtime.h>
#include <cmath>

#define NT 144

typedef float v2f __attribute__((ext_vector_type(2)));

// Round-5: latency-bound fix.
//   * __launch_bounds__(256,4): cap VGPR at 128 -> 4 waves/SIMD (was likely 2).
//   * #pragma unroll 1: only one chunk's 4 element-chains live -> fits the cap.
//   * Even/odd split Horner: N(x) = E(x^2) + x*O(x^2). Same coefficients and
//     op count (19 pk-fma), but dep-chain depth 18 -> ~10, and v_log_f32
//     overlaps the Horner chain instead of serializing after it.
//   * Packed X build: X = sp*(tj,tj) + (nspdt, nspdt-spTau)  (one v_pk_fma).
// Work map unchanged (proven coalescing): 4 threads/row, c = tid&3,
// row = blockIdx.x*64 + (tid>>2); thread's float4 chunks = c + 4k, k=0..8.
// A wave's store = 16 rows x contiguous 64 B (64-B aligned HBM sectors);
// adjacent k complete the 128-B L2 lines.

__global__ __launch_bounds__(256, 4) void dynangio_kernel(
    const float* __restrict__ x,
    const float* __restrict__ t,
    const float* __restrict__ alpha,
    const float* __restrict__ R,
    float* __restrict__ out,
    int B)
{
    __shared__ alignas(16) float sh_t[NT];
    __shared__ alignas(16) float sh_re[NT];
    const int tid = threadIdx.x;
    if (tid < NT) {
        sh_t[tid]  = t[tid];
        sh_re[tid] = R[tid] * sinf(alpha[tid] * 0.017453292519943295f);
    }
    __syncthreads();

    const int c   = tid & 3;          // which j-chunk phase
    const int row = blockIdx.x * 64 + (tid >> 2);
    if (row >= B) return;

    const float4 xi = reinterpret_cast<const float4*>(x)[row];
    const float dt  = xi.x;
    const float s   = xi.y;
    const float p   = xi.z;
    const float amp = xi.w;

    const float T1B   = 1.65f;
    const float TAU   = 1.8f;
    const float LOG2E = 1.4426950408889634f;

    const float u  = p * s;            // a-1 in [0,1)
    const float a  = 1.0f + u;
    const float sp = s + (1.0f / T1B);

    // Gamma(1+u), u in [0,1): A&S 6.1.36, |err| <= 3e-7
    float g = 0.035868343f;
    g = g * u - 0.193527818f;
    g = g * u + 0.482199394f;
    g = g * u - 0.756704078f;
    g = g * u + 0.918206857f;
    g = g * u - 0.897056937f;
    g = g * u + 0.988205891f;
    g = g * u - 0.577191652f;
    g = g * u + 1.0f;
    const float Ga1 = (1.0f + u) * g;  // Gamma(a+1)

    // d_k = prod_{m=k..18}(a+m) -- named scalars (VGPRs, no scratch)
    const float d18 = a + 18.0f;
    const float d17 = (a + 17.0f) * d18;
    const float d16 = (a + 16.0f) * d17;
    const float d15 = (a + 15.0f) * d16;
    const float d14 = (a + 14.0f) * d15;
    const float d13 = (a + 13.0f) * d14;
    const float d12 = (a + 12.0f) * d13;
    const float d11 = (a + 11.0f) * d12;
    const float d10 = (a + 10.0f) * d11;
    const float d9  = (a +  9.0f) * d10;
    const float d8  = (a +  8.0f) * d9;
    const float d7  = (a +  7.0f) * d8;
    const float d6  = (a +  6.0f) * d7;
    const float d5  = (a +  5.0f) * d6;
    const float d4  = (a +  4.0f) * d5;
    const float d3  = (a +  3.0f) * d4;
    const float d2  = (a +  2.0f) * d3;
    const float d1  = (a +  1.0f) * d2;

    const float invDG = 1.0f / (d1 * Ga1);

    // SF = 2*exp(-dt/T1B)*(s/sp)^a  (per-row hw transc, amortized)
    const float SF = 2.0f * __builtin_amdgcn_exp2f(
        a * (__builtin_amdgcn_logf(s) - __builtin_amdgcn_logf(sp))
        - dt * (LOG2E / T1B));

    const float crow  = amp * SF * invDG;
    const float nspdt = -sp * dt;
    const float spTau = sp * TAU;
    v2f dtv; dtv.x = nspdt; dtv.y = nspdt - spTau;

    // N(x) = x^18 + d18 x^17 + ... + d2 x + d1, evaluated as E(x^2) + x*O(x^2)
    auto elem = [&](float tj, float cr) -> float {
        v2f tv; tv.x = tj; tv.y = tj;
        v2f X = sp * tv + dtv;             // pk_fma: (x1, x2)
        X.y = fmaxf(X.y, 0.0f);            // x2 clamp; x1 > 0.48 always
        const v2f Z = X * X;               // pk_mul
        // even part: z^9 + d17 z^8 + d15 z^7 + ... + d1   (9 pk_fma)
        v2f NE = Z + d17;
        NE = Z*NE + d15;  NE = Z*NE + d13;  NE = Z*NE + d11;
        NE = Z*NE + d9;   NE = Z*NE + d7;   NE = Z*NE + d5;
        NE = Z*NE + d3;   NE = Z*NE + d1;
        // odd part: d18 z^8 + d16 z^7 + ... + d2           (8 pk_fma)
        v2f NO = Z*d18 + d16;
        NO = Z*NO + d14;  NO = Z*NO + d12;  NO = Z*NO + d10;
        NO = Z*NO + d8;   NO = Z*NO + d6;   NO = Z*NO + d4;
        NO = Z*NO + d2;
        const v2f N = X*NO + NE;           // pk_fma: full 18-term N
        // x^a * e^-x = exp2(a*log2(x) - x*log2e);  x2==0 -> exp2(-inf)=0
        v2f L; L.x = __builtin_amdgcn_logf(X.x); L.y = __builtin_amdgcn_logf(X.y);
        const v2f Ee = a * L - X * LOG2E;  // packed fma
        const float e1 = __builtin_amdgcn_exp2f(Ee.x);
        const float e2 = __builtin_amdgcn_exp2f(Ee.y);
        return cr * __builtin_fmaf(N.x, e1, -(N.y * e2));
    };

    float4* __restrict__ orow4 = reinterpret_cast<float4*>(out + (size_t)row * NT);
    const float4* sh_t4  = reinterpret_cast<const float4*>(sh_t);
    const float4* sh_re4 = reinterpret_cast<const float4*>(sh_re);

    #pragma unroll 1
    for (int k = 0; k < 9; ++k) {
        const int ch = c + 4 * k;             // chunk index 0..35
        const float4 tj4 = sh_t4[ch];
        const float4 re4 = sh_re4[ch];
        float4 res;
        res.x = elem(tj4.x, crow * re4.x);
        res.y = elem(tj4.y, crow * re4.y);
        res.z = elem(tj4.z, crow * re4.z);
        res.w = elem(tj4.w, crow * re4.w);
        orow4[ch] = res;
    }
}

extern "C" void kernel_launch(void* const* d_in, const int* in_sizes, int n_in,
                              void* d_out, int out_size, void* d_ws, size_t ws_size,
                              hipStream_t stream) {
    const float* x     = (const float*)d_in[0];
    const float* t     = (const float*)d_in[1];
    const float* alpha = (const float*)d_in[2];
    const float* R     = (const float*)d_in[3];
    float* out = (float*)d_out;

    const int B = in_sizes[0] / 4;
    const int rows_per_block = 64;
    const int blocks = (B + rows_per_block - 1) / rows_per_block;
    hipLaunchKernelGGL(dynangio_kernel, dim3(blocks), dim3(256), 0, stream,
                       x, t, alpha, R, out, B);
}